// Round 4
// baseline (399.033 us; speedup 1.0000x reference)
//
#include <hip/hip_runtime.h>
#include <hip/hip_cooperative_groups.h>
#include <stdint.h>

#define HIDDEN 2560
#define NHEADS 8
#define HD 512
#define QDIM (NHEADS * HD)        // 4096
#define SEQ 32768
#define CHUNK 128
#define NCHUNK (SEQ / CHUNK)      // 256
#define PART_ST (8 + QDIM)        // 4104 floats: den[8] + num[8][512]
#define SCALE 0.044194173824159216f // 1/sqrt(512)
#define NBLK 256                  // == CU count; 1 block/CU, co-resident
#define NTHR 256

// ws layout (floats):
//   [0 .. 5120)    q[4096], k[512], v[512]
//   [8192..12288)  attn
//   [16384 .. )    partials: NCHUNK x PART_ST (~4.2 MiB)
#define WS_Q    0
#define WS_K    4096
#define WS_V    4608
#define WS_ATT  8192
#define WS_PART 16384

__global__ __launch_bounds__(NTHR) void fused_attn(
    const float* __restrict__ x,
    const float* __restrict__ kvfull,
    const float* __restrict__ wq,
    const float* __restrict__ wk,
    const float* __restrict__ wv,
    const float* __restrict__ wo,
    const int* __restrict__ cur_pos,
    float* __restrict__ ws,
    float* __restrict__ out) {
  namespace cg = cooperative_groups;
  cg::grid_group grid = cg::this_grid();

  const int tid = threadIdx.x;
  const int lane = tid & 63;
  const int wid = tid >> 6;
  const int b = blockIdx.x;
  const int gw = b * 4 + wid;              // global wave id, 0..1023

  __shared__ float sc[CHUNK * NHEADS];     // 4 KB: exp(scores); stage-3 scratch
  __shared__ float4 vtmp[NHEADS * 128];    // 16 KB: phase-C combine buffer
  __shared__ float sLinv;

  // ================= stage 1: q/k/v GEMV (wave per row, 5 rows/wave) ========
  for (int r = gw; r < QDIM + 2 * HD; r += 4 * NBLK) {
    const float* w;
    if (r < QDIM) w = wq + (size_t)r * HIDDEN;
    else if (r < QDIM + HD) w = wk + (size_t)(r - QDIM) * HIDDEN;
    else w = wv + (size_t)(r - QDIM - HD) * HIDDEN;
    float acc = 0.f;
#pragma unroll
    for (int i = 0; i < 5; i++) {
      const int j = i * 512 + lane * 8;
      float4 a0 = *(const float4*)(w + j);
      float4 a1 = *(const float4*)(w + j + 4);
      float4 b0 = *(const float4*)(x + j);
      float4 b1 = *(const float4*)(x + j + 4);
      acc += a0.x * b0.x + a0.y * b0.y + a0.z * b0.z + a0.w * b0.w +
             a1.x * b1.x + a1.y * b1.y + a1.z * b1.z + a1.w * b1.w;
    }
#pragma unroll
    for (int off = 32; off > 0; off >>= 1) acc += __shfl_xor(acc, off);
    if (lane == 0) ws[WS_Q + r] = acc;
  }

  grid.sync();

  // ================= stage 2: attention partial, chunk = blockIdx ===========
  {
    const int cur = cur_pos[0];
    const float* K = kvfull;
    const float* V = kvfull + (size_t)SEQ * HD;
    const int s0 = b * CHUNK;

    // q fragments: lane holds q[h][lane*8 .. +8] for all 8 heads
    float qf[NHEADS][8];
#pragma unroll
    for (int h = 0; h < NHEADS; h++) {
      float4 a = *(const float4*)(ws + WS_Q + h * HD + lane * 8);
      float4 c = *(const float4*)(ws + WS_Q + h * HD + lane * 8 + 4);
      qf[h][0] = a.x; qf[h][1] = a.y; qf[h][2] = a.z; qf[h][3] = a.w;
      qf[h][4] = c.x; qf[h][5] = c.y; qf[h][6] = c.z; qf[h][7] = c.w;
    }

    // phase A: exp(scores). wave handles 32 consecutive positions
    for (int ii = 0; ii < CHUNK / 4; ii++) {
      const int scix = wid * (CHUNK / 4) + ii;
      const int s = s0 + scix;
      const float* krow = (s == cur) ? (ws + WS_K) : (K + (size_t)s * HD);
      float4 a = *(const float4*)(krow + lane * 8);
      float4 c = *(const float4*)(krow + lane * 8 + 4);
      float kb[8] = {a.x, a.y, a.z, a.w, c.x, c.y, c.z, c.w};
      float p[NHEADS];
#pragma unroll
      for (int h = 0; h < NHEADS; h++) {
        float t = 0.f;
#pragma unroll
        for (int e = 0; e < 8; e++) t += kb[e] * qf[h][e];
        p[h] = t;
      }
#pragma unroll
      for (int off = 32; off > 0; off >>= 1) {
#pragma unroll
        for (int h = 0; h < NHEADS; h++) p[h] += __shfl_xor(p[h], off);
      }
      if (lane == 0) {
#pragma unroll
        for (int h = 0; h < NHEADS; h++) sc[scix * NHEADS + h] = __expf(p[h] * SCALE);
      }
    }
    __syncthreads();

    float* pb = ws + WS_PART + (size_t)b * PART_ST;
    // den: wave wid reduces heads 2*wid, 2*wid+1
    {
      const int h0 = wid * 2;
      float s1 = sc[lane * NHEADS + h0]     + sc[(64 + lane) * NHEADS + h0];
      float s2 = sc[lane * NHEADS + h0 + 1] + sc[(64 + lane) * NHEADS + h0 + 1];
#pragma unroll
      for (int off = 32; off > 0; off >>= 1) {
        s1 += __shfl_xor(s1, off);
        s2 += __shfl_xor(s2, off);
      }
      if (lane == 0) { pb[h0] = s1; pb[h0 + 1] = s2; }
    }

    // phase C: num = sum exp(s)*V. 128 threads own 4 dims; 2 sy-halves (g)
    const int g = tid >> 7;
    const int tl = tid & 127;
    const int d0 = tl * 4;
    float4 acc8[NHEADS];
#pragma unroll
    for (int h = 0; h < NHEADS; h++) acc8[h] = make_float4(0.f, 0.f, 0.f, 0.f);
    for (int sy = g * (CHUNK / 2); sy < (g + 1) * (CHUNK / 2); sy++) {
      const int s = s0 + sy;
      const float* vrow = (s == cur) ? (ws + WS_V) : (V + (size_t)s * HD);
      float4 v4 = *(const float4*)(vrow + d0);
#pragma unroll
      for (int h = 0; h < NHEADS; h++) {
        const float pp = sc[sy * NHEADS + h];
        acc8[h].x += pp * v4.x; acc8[h].y += pp * v4.y;
        acc8[h].z += pp * v4.z; acc8[h].w += pp * v4.w;
      }
    }
    if (g == 1) {
#pragma unroll
      for (int h = 0; h < NHEADS; h++) vtmp[h * 128 + tl] = acc8[h];
    }
    __syncthreads();
    if (g == 0) {
#pragma unroll
      for (int h = 0; h < NHEADS; h++) {
        float4 o = vtmp[h * 128 + tl];
        o.x += acc8[h].x; o.y += acc8[h].y; o.z += acc8[h].z; o.w += acc8[h].w;
        *(float4*)(pb + 8 + h * HD + d0) = o;
      }
    }
  }

  grid.sync();

  // ================= stage 3: combine. block b -> dims [b*16, b*16+16) ======
  {
    const int h = b >> 5;                  // 16 dims per block, 512/head
    const float* part = ws + WS_PART;
    if (wid == 0) {
      float d_ = 0.f;
#pragma unroll
      for (int q4 = 0; q4 < 4; q4++)
        d_ += part[(size_t)(q4 * 64 + lane) * PART_ST + h];
#pragma unroll
      for (int off = 32; off > 0; off >>= 1) d_ += __shfl_xor(d_, off);
      if (lane == 0) sLinv = 1.f / d_;
    }
    const int dim = tid & 15;
    const int bg = tid >> 4;               // 16 b-groups of 16
    const int dl = (b * 16 + dim) & (HD - 1);
    float a_ = 0.f;
    for (int bb = bg * 16; bb < bg * 16 + 16; bb++)
      a_ += part[(size_t)bb * PART_ST + 8 + h * HD + dl];
    __syncthreads();                       // sc reuse: phase-2 reads done
    sc[tid] = a_;
    __syncthreads();
    if (tid < 16) {
      float s_ = 0.f;
#pragma unroll
      for (int q4 = 0; q4 < 16; q4++) s_ += sc[q4 * 16 + tid];
      ws[WS_ATT + b * 16 + tid] = s_ * sLinv;
    }
  }

  grid.sync();

  // ================= stage 4: output GEMV (wave per row) ====================
  for (int r = gw; r < HIDDEN; r += 4 * NBLK) {
    const float* w = wo + (size_t)r * QDIM;
    float acc = 0.f;
#pragma unroll
    for (int i = 0; i < 8; i++) {
      const int j = i * 512 + lane * 8;
      float4 w0 = *(const float4*)(w + j);
      float4 w1 = *(const float4*)(w + j + 4);
      float4 a0 = *(const float4*)(ws + WS_ATT + j);
      float4 a1 = *(const float4*)(ws + WS_ATT + j + 4);
      acc += w0.x * a0.x + w0.y * a0.y + w0.z * a0.z + w0.w * a0.w +
             w1.x * a1.x + w1.y * a1.y + w1.z * a1.z + w1.w * a1.w;
    }
#pragma unroll
    for (int off = 32; off > 0; off >>= 1) acc += __shfl_xor(acc, off);
    if (lane == 0) out[r] = acc;
  }
}

extern "C" void kernel_launch(void* const* d_in, const int* in_sizes, int n_in,
                              void* d_out, int out_size, void* d_ws, size_t ws_size,
                              hipStream_t stream) {
  (void)in_sizes; (void)n_in; (void)out_size; (void)ws_size;
  const float* x      = (const float*)d_in[0];
  // d_in[1] = kv_sliding (unused by reference)
  const float* kvfull = (const float*)d_in[2];
  const float* wq     = (const float*)d_in[3];
  const float* wk     = (const float*)d_in[4];
  const float* wv     = (const float*)d_in[5];
  const float* wo     = (const float*)d_in[6];
  const int* cur_pos  = (const int*)d_in[7];
  // d_in[8] = ring_pos (unused by reference)
  float* out = (float*)d_out;
  float* ws = (float*)d_ws;

  void* args[] = {(void*)&x, (void*)&kvfull, (void*)&wq, (void*)&wk, (void*)&wv,
                  (void*)&wo, (void*)&cur_pos, (void*)&ws, (void*)&out};
  hipLaunchCooperativeKernel((void*)fused_attn, dim3(NBLK), dim3(NTHR),
                             args, 0, stream);
}